// Round 1
// baseline (1435.283 us; speedup 1.0000x reference)
//
#include <hip/hip_runtime.h>

// Problem constants
#define NB   32      // batch
#define NC   24      // image channels
#define ND   12      // spatial
#define NN   144     // ND*ND objects
#define NK   26      // NC+2 channels incl coords
#define QD   11
#define GH   256
#define FOUT 10

// Workspace layout (floats)
//   L  : [32][144][256]  offset 0        (1179648)
//   R  : [32][144][256]  offset 1179648  (1179648)
//   QC : [32][256]       offset 2359296  (8192)
//   S  : [32][256]       offset 2367488  (8192)
#define L_OFF  0
#define R_OFF  1179648
#define QC_OFF 2359296
#define S_OFF  2367488

// ---------------------------------------------------------------------------
// Precompute L and R: per-object projections through the left/right halves of
// Wg1. idx = ((which*NB + b)*NN + p)*GH + h, which=0 -> L, which=1 -> R.
// Within a block all 256 threads share (which,b,p); h = threadIdx.x.
// image reads are wave-uniform (scalar-loadable), Wg1 reads coalesced.
// ---------------------------------------------------------------------------
__global__ __launch_bounds__(256) void prep_lr(const float* __restrict__ image,
                                               const float* __restrict__ Wg1,
                                               float* __restrict__ LR) {
  int idx   = blockIdx.x * 256 + threadIdx.x;
  int h     = idx & 255;
  int rest  = idx >> 8;          // which*NB*NN + b*NN + p
  int p     = rest % NN;
  int rest2 = rest / NN;         // which*NB + b
  int b     = rest2 & (NB - 1);
  int which = rest2 >> 5;
  const float* Wrow = Wg1 + which * NK * GH;
  const float* img  = image + b * (NC * NN) + p;
  float acc = 0.f;
#pragma unroll
  for (int c = 0; c < NC; ++c) acc += img[c * NN] * Wrow[c * GH + h];
  int i = p / ND, j = p - i * ND;
  const float inv = 1.0f / (ND - 1);
  acc += (j * inv) * Wrow[24 * GH + h];   // cx channel = coord over x (fast axis)
  acc += (i * inv) * Wrow[25 * GH + h];   // cy channel = coord over y
  LR[idx] = acc;
}

// ---------------------------------------------------------------------------
// QC[b,h] = q[b]·Wg1[52:63,h] + bg1[h]; also zero the pair-sum accumulator S.
// ---------------------------------------------------------------------------
__global__ __launch_bounds__(256) void prep_qc(const float* __restrict__ question,
                                               const float* __restrict__ Wg1,
                                               const float* __restrict__ bg1,
                                               float* __restrict__ QC,
                                               float* __restrict__ S) {
  int b = blockIdx.x, h = threadIdx.x;
  float acc = bg1[h];
#pragma unroll
  for (int t = 0; t < QD; ++t)
    acc += question[b * QD + t] * Wg1[(2 * NK + t) * GH + h];
  QC[b * GH + h] = acc;
  S[b * GH + h]  = 0.f;
}

// ---------------------------------------------------------------------------
// Main pair GEMM. Tile: 64 pairs x 64 cols, K=256 in chunks of 16.
// A[m][k] = relu(L[b, p/144, k] + R[b, p%144, k] + QC[b, k]) generated on the
// fly into LDS. Epilogue: +bg2, relu, column-sum, one atomicAdd per column.
// Grid: (324 pair tiles, 4 col tiles, 32 batches), 256 threads (16x16, 4x4).
// ---------------------------------------------------------------------------
__global__ __launch_bounds__(256) void pair_gemm(const float* __restrict__ L,
                                                 const float* __restrict__ R,
                                                 const float* __restrict__ QC,
                                                 const float* __restrict__ Wg2,
                                                 const float* __restrict__ bg2,
                                                 float* __restrict__ S) {
  const int b    = blockIdx.z;
  const int col0 = blockIdx.y * 64;
  const int p0   = blockIdx.x * 64;
  const int t    = threadIdx.x;
  const int tx   = t & 15;        // output col group
  const int ty   = t >> 4;        // output row group

  __shared__ __align__(16) float As[16][64];  // [k][m]
  __shared__ __align__(16) float Bs[16][64];  // [k][n]
  __shared__ float csum[64];

  const float* Lb  = L + b * NN * GH;
  const float* Rb  = R + b * NN * GH;
  const float* QCb = QC + b * GH;

  // tile-load role: thread covers k=kk_ld, rows m4..m4+3
  const int kk_ld = t >> 4;          // 0..15
  const int m4    = (t & 15) << 2;   // 0,4,...,60

  int pi[4], pj[4];
#pragma unroll
  for (int e = 0; e < 4; ++e) {
    int p = p0 + m4 + e;
    pi[e] = p / NN;
    pj[e] = p - pi[e] * NN;
  }

  float acc[4][4] = {};

  for (int k0 = 0; k0 < GH; k0 += 16) {
    float qv = QCb[k0 + kk_ld];
    float tmp[4];
#pragma unroll
    for (int e = 0; e < 4; ++e) {
      float v = Lb[pi[e] * GH + k0 + kk_ld] + Rb[pj[e] * GH + k0 + kk_ld] + qv;
      tmp[e] = v > 0.f ? v : 0.f;
    }
    *(float4*)&As[kk_ld][m4] = make_float4(tmp[0], tmp[1], tmp[2], tmp[3]);
    *(float4*)&Bs[kk_ld][m4] =
        *(const float4*)&Wg2[(k0 + kk_ld) * GH + col0 + m4];
    __syncthreads();
#pragma unroll
    for (int kk = 0; kk < 16; ++kk) {
      float4 av = *(float4*)&As[kk][ty << 2];
      float4 bv = *(float4*)&Bs[kk][tx << 2];
      float aa[4] = {av.x, av.y, av.z, av.w};
      float bb[4] = {bv.x, bv.y, bv.z, bv.w};
#pragma unroll
      for (int r = 0; r < 4; ++r)
#pragma unroll
        for (int c = 0; c < 4; ++c) acc[r][c] += aa[r] * bb[c];
    }
    __syncthreads();
  }

  // epilogue: +bg2, relu, sum over this thread's 4 rows per column
  float cs[4];
#pragma unroll
  for (int c = 0; c < 4; ++c) {
    float bgv = bg2[col0 + (tx << 2) + c];
    float sum = 0.f;
#pragma unroll
    for (int r = 0; r < 4; ++r) {
      float v = acc[r][c] + bgv;
      sum += v > 0.f ? v : 0.f;
    }
    cs[c] = sum;
  }
  if (t < 64) csum[t] = 0.f;
  __syncthreads();
#pragma unroll
  for (int c = 0; c < 4; ++c) atomicAdd(&csum[(tx << 2) + c], cs[c]);
  __syncthreads();
  if (t < 64) atomicAdd(&S[b * GH + col0 + t], csum[t]);
}

// ---------------------------------------------------------------------------
// Final f-MLP: out = relu(S@Wf1+bf1)@Wf2+bf2. One block per batch.
// ---------------------------------------------------------------------------
__global__ __launch_bounds__(256) void final_mlp(const float* __restrict__ S,
                                                 const float* __restrict__ Wf1,
                                                 const float* __restrict__ bf1,
                                                 const float* __restrict__ Wf2,
                                                 const float* __restrict__ bf2,
                                                 float* __restrict__ out) {
  __shared__ float sS[GH];
  __shared__ float oS[GH];
  int b = blockIdx.x, h = threadIdx.x;
  sS[h] = S[b * GH + h];
  __syncthreads();
  float acc = bf1[h];
#pragma unroll 8
  for (int k = 0; k < GH; ++k) acc += sS[k] * Wf1[k * GH + h];
  oS[h] = acc > 0.f ? acc : 0.f;
  __syncthreads();
  if (h < FOUT) {
    float o = bf2[h];
#pragma unroll 8
    for (int k = 0; k < GH; ++k) o += oS[k] * Wf2[k * FOUT + h];
    out[b * FOUT + h] = o;
  }
}

extern "C" void kernel_launch(void* const* d_in, const int* in_sizes, int n_in,
                              void* d_out, int out_size, void* d_ws, size_t ws_size,
                              hipStream_t stream) {
  const float* image    = (const float*)d_in[0];
  const float* question = (const float*)d_in[1];
  const float* Wg1      = (const float*)d_in[2];
  const float* bg1      = (const float*)d_in[3];
  const float* Wg2      = (const float*)d_in[4];
  const float* bg2      = (const float*)d_in[5];
  const float* Wf1      = (const float*)d_in[6];
  const float* bf1      = (const float*)d_in[7];
  const float* Wf2      = (const float*)d_in[8];
  const float* bf2      = (const float*)d_in[9];
  float* out = (float*)d_out;
  float* ws  = (float*)d_ws;

  float* Lp  = ws + L_OFF;
  float* Rp  = ws + R_OFF;
  float* QCp = ws + QC_OFF;
  float* Sp  = ws + S_OFF;

  // 2*NB*NN*GH / 256 = 9216 blocks
  prep_lr<<<9216, 256, 0, stream>>>(image, Wg1, ws);
  prep_qc<<<NB, 256, 0, stream>>>(question, Wg1, bg1, QCp, Sp);
  pair_gemm<<<dim3(NN * NN / 64, GH / 64, NB), 256, 0, stream>>>(
      Lp, Rp, QCp, Wg2, bg2, Sp);
  final_mlp<<<NB, 256, 0, stream>>>(Sp, Wf1, bf1, Wf2, bf2, out);
}

// Round 2
// 196.850 us; speedup vs baseline: 7.2912x; 7.2912x over previous
//
#include <hip/hip_runtime.h>
#include <hip/hip_bf16.h>

// Problem constants
#define NB   32      // batch
#define NC   24      // image channels
#define ND   12      // spatial
#define NN   144     // ND*ND objects
#define QD   11
#define GH   256
#define FOUT 10
#define NSLOT 16     // partial-sum slices for S

typedef unsigned short u16;
typedef __attribute__((ext_vector_type(8))) short bf16x8;
typedef __attribute__((ext_vector_type(4))) float f32x4;

// Workspace layout (u16 elements unless noted)
//   Lb   : [32][144][256] bf16   off 0          (1179648)
//   Rb   : [32][144][256] bf16   off 1179648    (1179648)
//   QCb  : [32][256]      bf16   off 2359296    (8192)
//   Bswz : [128 frags][64][8] bf16 off 2367488  (65536)   (frag = kt*16 + nt)
//   Spart: [16][32][256]  f32    byte off 4866048 (131072 floats)
#define LB_OFF   0
#define RB_OFF   1179648
#define QC_OFF   2359296
#define BS_OFF   2367488
#define SP_BYTE  4866048

__device__ inline float b2f(u16 v) {
  union { unsigned u; float f; } c; c.u = ((unsigned)v) << 16; return c.f;
}
__device__ inline u16 f2b(float f) {
  __hip_bfloat16 h = __float2bfloat16(f);
  return *reinterpret_cast<u16*>(&h);
}

// ---------------------------------------------------------------------------
// L/R projections through left/right halves of Wg1, output bf16.
// idx = ((which*NB + b)*NN + p)*GH + h
// ---------------------------------------------------------------------------
__global__ __launch_bounds__(256) void prep_lr(const float* __restrict__ image,
                                               const float* __restrict__ Wg1,
                                               u16* __restrict__ LRb) {
  int idx   = blockIdx.x * 256 + threadIdx.x;
  int h     = idx & 255;
  int rest  = idx >> 8;
  int p     = rest % NN;
  int rest2 = rest / NN;
  int b     = rest2 & (NB - 1);
  int which = rest2 >> 5;
  const float* Wrow = Wg1 + which * (NC + 2) * GH;
  const float* img  = image + b * (NC * NN) + p;
  float acc = 0.f;
#pragma unroll
  for (int c = 0; c < NC; ++c) acc += img[c * NN] * Wrow[c * GH + h];
  int i = p / ND, j = p - i * ND;
  const float inv = 1.0f / (ND - 1);
  acc += (j * inv) * Wrow[24 * GH + h];
  acc += (i * inv) * Wrow[25 * GH + h];
  LRb[idx] = f2b(acc);
}

// ---------------------------------------------------------------------------
// QC[b,h] = q[b]·Wg1[52:63,h] + bg1[h] (bf16); zero Spart.
// ---------------------------------------------------------------------------
__global__ __launch_bounds__(256) void prep_qc(const float* __restrict__ question,
                                               const float* __restrict__ Wg1,
                                               const float* __restrict__ bg1,
                                               u16* __restrict__ QCb,
                                               float* __restrict__ Spart) {
  int b = blockIdx.x, h = threadIdx.x;
  float acc = bg1[h];
#pragma unroll
  for (int t = 0; t < QD; ++t)
    acc += question[b * QD + t] * Wg1[(2 * (NC + 2) + t) * GH + h];
  QCb[b * GH + h] = f2b(acc);
  int idx = b * 256 + h;
#pragma unroll
  for (int s = 0; s < NSLOT; ++s) Spart[s * (NB * GH) + idx] = 0.f;
}

// ---------------------------------------------------------------------------
// Pre-swizzle Wg2 into bf16 MFMA B-fragment order.
// frag fid = kt*16 + nt (kt: K/32, nt: N/16); element (l, e):
//   k = kt*32 + (l>>4)*8 + e, n = nt*16 + (l&15)
// ---------------------------------------------------------------------------
__global__ __launch_bounds__(256) void prep_wg2(const float* __restrict__ Wg2,
                                                u16* __restrict__ Bswz) {
  int idx = blockIdx.x * 256 + threadIdx.x;   // 0..65535
  int e   = idx & 7;
  int l   = (idx >> 3) & 63;
  int fid = idx >> 9;                          // 0..127
  int kt  = fid >> 4, nt = fid & 15;
  int k = kt * 32 + ((l >> 4) << 3) + e;
  int n = (nt << 4) + (l & 15);
  Bswz[idx] = f2b(Wg2[k * GH + n]);
}

// ---------------------------------------------------------------------------
// MFMA pair GEMM. Block = 256 thr (4 waves), tile = 64 pairs x 256 cols.
// Per K-step(32): build A-tile (relu(L+R+QC)) in LDS in fragment layout,
// each wave: 4x ds_read_b128 (A) + 4x dwordx4 (B) + 16 MFMA.
// Epilogue: +bg2, relu, row-sum, shfl-reduce, atomic into Spart slice.
// Grid: (324 m-tiles, 32 batches).
// ---------------------------------------------------------------------------
__global__ __launch_bounds__(256) void pair_gemm(const u16* __restrict__ Lb,
                                                 const u16* __restrict__ Rb,
                                                 const u16* __restrict__ QCb,
                                                 const u16* __restrict__ Bswz,
                                                 const float* __restrict__ bg2,
                                                 float* __restrict__ Spart) {
  const int mtile = blockIdx.x;
  const int b     = blockIdx.y;
  const int p0    = mtile * 64;
  const int t     = threadIdx.x;
  const int w     = t >> 6;        // wave id = A-frag id this thread builds
  const int l     = t & 63;

  __shared__ __align__(16) u16 As[4 * 64 * 8];   // 4 frags x 64 lanes x 8 bf16

  // A-build role: row within tile, k-octet within K-step
  const int row   = (w << 4) | (l & 15);
  const int p     = p0 + row;
  const int i     = p / NN;
  const int j     = p - i * NN;
  const int klane = (l >> 4) << 3;               // 0,8,16,24
  const u16* Lrow = Lb + (b * NN + i) * GH + klane;
  const u16* Rrow = Rb + (b * NN + j) * GH + klane;
  const u16* Qrow = QCb + b * GH + klane;
  const u16* Bw   = Bswz + (size_t)l * 8;        // + (fid*64)*8 later

  f32x4 acc[4][4] = {};

  for (int kt = 0; kt < 8; ++kt) {
    const int k0 = kt * 32;
    bf16x8 lv = *(const bf16x8*)(Lrow + k0);
    bf16x8 rv = *(const bf16x8*)(Rrow + k0);
    bf16x8 qv = *(const bf16x8*)(Qrow + k0);
    u16 outv[8];
#pragma unroll
    for (int e = 0; e < 8; ++e) {
      float v = b2f((u16)lv[e]) + b2f((u16)rv[e]) + b2f((u16)qv[e]);
      outv[e] = f2b(v > 0.f ? v : 0.f);
    }
    if (kt) __syncthreads();                     // prior reads done
    *(bf16x8*)&As[((w << 6) | l) << 3] = *(bf16x8*)outv;
    __syncthreads();

    bf16x8 af[4];
#pragma unroll
    for (int mf = 0; mf < 4; ++mf)
      af[mf] = *(const bf16x8*)&As[((mf << 6) | l) << 3];
    bf16x8 bfr[4];
#pragma unroll
    for (int nt = 0; nt < 4; ++nt) {
      int fid = kt * 16 + (w << 2) + nt;
      bfr[nt] = *(const bf16x8*)(Bw + (size_t)fid * 512);
    }
#pragma unroll
    for (int mf = 0; mf < 4; ++mf)
#pragma unroll
      for (int nt = 0; nt < 4; ++nt)
        acc[mf][nt] = __builtin_amdgcn_mfma_f32_16x16x32_bf16(
            af[mf], bfr[nt], acc[mf][nt], 0, 0, 0);
  }

  // Epilogue: C/D layout col = l&15, row = (l>>4)*4 + reg.
  const int slot = mtile & (NSLOT - 1);
  float* Sp = Spart + slot * (NB * GH) + b * GH;
#pragma unroll
  for (int nt = 0; nt < 4; ++nt) {
    int n = (w << 6) + (nt << 4) + (l & 15);
    float bgv = bg2[n];
    float s = 0.f;
#pragma unroll
    for (int mf = 0; mf < 4; ++mf)
#pragma unroll
      for (int r = 0; r < 4; ++r) {
        float v = acc[mf][nt][r] + bgv;
        s += v > 0.f ? v : 0.f;
      }
    s += __shfl_xor(s, 16, 64);
    s += __shfl_xor(s, 32, 64);
    if ((l >> 4) == 0) atomicAdd(&Sp[n], s);
  }
}

// ---------------------------------------------------------------------------
// Final f-MLP: S = sum of slices; out = relu(S@Wf1+bf1)@Wf2+bf2.
// ---------------------------------------------------------------------------
__global__ __launch_bounds__(256) void final_mlp(const float* __restrict__ Spart,
                                                 const float* __restrict__ Wf1,
                                                 const float* __restrict__ bf1,
                                                 const float* __restrict__ Wf2,
                                                 const float* __restrict__ bf2,
                                                 float* __restrict__ out) {
  __shared__ float sS[GH];
  __shared__ float oS[GH];
  int b = blockIdx.x, h = threadIdx.x;
  float sv = 0.f;
#pragma unroll
  for (int s = 0; s < NSLOT; ++s) sv += Spart[s * (NB * GH) + b * GH + h];
  sS[h] = sv;
  __syncthreads();
  float acc = bf1[h];
#pragma unroll 8
  for (int k = 0; k < GH; ++k) acc += sS[k] * Wf1[k * GH + h];
  oS[h] = acc > 0.f ? acc : 0.f;
  __syncthreads();
  if (h < FOUT) {
    float o = bf2[h];
#pragma unroll 8
    for (int k = 0; k < GH; ++k) o += oS[k] * Wf2[k * FOUT + h];
    out[b * FOUT + h] = o;
  }
}

extern "C" void kernel_launch(void* const* d_in, const int* in_sizes, int n_in,
                              void* d_out, int out_size, void* d_ws, size_t ws_size,
                              hipStream_t stream) {
  const float* image    = (const float*)d_in[0];
  const float* question = (const float*)d_in[1];
  const float* Wg1      = (const float*)d_in[2];
  const float* bg1      = (const float*)d_in[3];
  const float* Wg2      = (const float*)d_in[4];
  const float* bg2      = (const float*)d_in[5];
  const float* Wf1      = (const float*)d_in[6];
  const float* bf1      = (const float*)d_in[7];
  const float* Wf2      = (const float*)d_in[8];
  const float* bf2      = (const float*)d_in[9];
  float* out = (float*)d_out;

  u16*   wsb   = (u16*)d_ws;
  u16*   Lbp   = wsb + LB_OFF;
  u16*   Rbp   = wsb + RB_OFF;
  u16*   QCp   = wsb + QC_OFF;
  u16*   Bswz  = wsb + BS_OFF;
  float* Spart = (float*)((char*)d_ws + SP_BYTE);

  prep_lr<<<9216, 256, 0, stream>>>(image, Wg1, Lbp);      // writes L then R halves
  prep_wg2<<<256, 256, 0, stream>>>(Wg2, Bswz);
  prep_qc<<<NB, 256, 0, stream>>>(question, Wg1, bg1, QCp, Spart);
  pair_gemm<<<dim3(NN * NN / 64, NB), 256, 0, stream>>>(Lbp, Rbp, QCp, Bswz,
                                                        bg2, Spart);
  final_mlp<<<NB, 256, 0, stream>>>(Spart, Wf1, bf1, Wf2, bf2, out);
}